// Round 4
// baseline (254.641 us; speedup 1.0000x reference)
//
#include <hip/hip_runtime.h>
#include <hip/hip_bf16.h>
#include <stdint.h>

typedef __attribute__((ext_vector_type(8))) short  short8;   // 8 bf16 (4 VGPR) MFMA A/B frag
typedef __attribute__((ext_vector_type(4))) short  short4v;
typedef __attribute__((ext_vector_type(4))) float  float4v;  // MFMA C/D frag

#define MFMA16(a, b, c) __builtin_amdgcn_mfma_f32_16x16x32_bf16((a), (b), (c), 0, 0, 0)

#define S_LEN  4096
#define NBATCH 4
#define EMB    1024
#define DD     64
#define NROWS  (NBATCH * S_LEN)  // 16384
#define SCL2   0.1803368801111204f  // (1/sqrt(64)) * log2(e)

static __device__ __forceinline__ short f2bf(float f) {
  uint32_t u = __float_as_uint(f);
  return (short)((u + 0x7FFFu + ((u >> 16) & 1u)) >> 16);
}
static __device__ __forceinline__ unsigned pk2(float a, float b) {
  union { __hip_bfloat162 h; unsigned u; } z;
  z.h = __float22bfloat162_rn(make_float2(a, b));
  return z.u;
}
static __device__ __forceinline__ short8 cvt8(float4v a, float4v b) {
  union { unsigned u[4]; short8 s; } z;
  z.u[0] = pk2(a[0], a[1]); z.u[1] = pk2(a[2], a[3]);
  z.u[2] = pk2(b[0], b[1]); z.u[3] = pk2(b[2], b[3]);
  return z.s;
}

// ============ Kernel 0: W fp32 -> bf16, reordered into 32-k panels ============
// Wb2 layout: [32 panels][192 rows][32 k] bf16; rows 0-63=Wq, 64-127=Wk, 128-191=Wv.
__global__ void wcvt_kernel(const float* __restrict__ Wq, const float* __restrict__ Wk,
                            const float* __restrict__ Wv, short* __restrict__ Wb2) {
  const int t   = blockIdx.x * 256 + threadIdx.x;  // 0..24575, 8 elems each
  const int row = t >> 7;
  const int k   = (t & 127) * 8;
  const float* src = (row < 64) ? (Wq + (size_t)row * EMB)
                   : (row < 128) ? (Wk + (size_t)(row - 64) * EMB)
                                 : (Wv + (size_t)(row - 128) * EMB);
  float4v a = *(const float4v*)(src + k);
  float4v b = *(const float4v*)(src + k + 4);
  *(short8*)(Wb2 + (((k >> 5) * 192 + row) << 5) + (k & 31)) = cvt8(a, b);
}

// ======================= Kernel 1: QKV projection GEMM =======================
// Barrier-free: 1024 blocks x 4 waves, 16 x-rows per block. Wave w owns frags
// {Q_w, K_w, V_w} (i=0,1,2) so the V operand-swap is uniform at unroll index
// i==2. A-frags straight from x (all 4 waves same rows -> L1 broadcast);
// B-frags from L2-resident bf16 panels; 1-step register prefetch; no LDS.
__global__ __launch_bounds__(256, 4) void qkv_kernel(
    const float* __restrict__ x, const short* __restrict__ Wb2,
    short* __restrict__ Qb, short* __restrict__ Kb, short* __restrict__ Vt) {
  const int tid  = threadIdx.x;
  const int w    = tid >> 6;
  const int lane = tid & 63;
  const int ln   = lane & 15;
  const int quad = lane >> 4;
  const int m0   = blockIdx.x * 16;

  const float* xp = x + (size_t)(m0 + ln) * EMB + quad * 8;
  const short* wp[3];
#pragma unroll
  for (int i = 0; i < 3; ++i)
    wp[i] = Wb2 + (size_t)(i * 64 + w * 16 + ln) * 32 + quad * 8;  // panel 0 row

  const float4v zz = {0.f, 0.f, 0.f, 0.f};
  float4v acc[3] = {zz, zz, zz};

  // preload step 0
  float4v a0 = *(const float4v*)(xp);
  float4v a1 = *(const float4v*)(xp + 4);
  short8 bpf[3];
#pragma unroll
  for (int i = 0; i < 3; ++i) bpf[i] = *(const short8*)(wp[i]);

  for (int s = 0; s < 32; ++s) {
    const short8 xf = cvt8(a0, a1);
    short8 bf[3];
#pragma unroll
    for (int i = 0; i < 3; ++i) bf[i] = bpf[i];
    const int sn = (s + 1 < 32) ? s + 1 : 31;  // harmless re-load on last step
    a0 = *(const float4v*)(xp + sn * 32);
    a1 = *(const float4v*)(xp + sn * 32 + 4);
#pragma unroll
    for (int i = 0; i < 3; ++i)
      bpf[i] = *(const short8*)(wp[i] + (size_t)sn * 6144);
    acc[0] = MFMA16(xf, bf[0], acc[0]);   // Q
    acc[1] = MFMA16(xf, bf[1], acc[1]);   // K
    acc[2] = MFMA16(bf[2], xf, acc[2]);   // V, swapped -> transposed output
  }

  // epilogue
  const int b  = m0 >> 12;
  const int sb = m0 & (S_LEN - 1);
#pragma unroll
  for (int r = 0; r < 4; ++r) {
    const int row = m0 + quad * 4 + r;          // Q/K: C row = x-row
    Qb[(size_t)row * DD + w * 16 + ln] = f2bf(acc[0][r]);
    Kb[(size_t)row * DD + w * 16 + ln] = f2bf(acc[1][r]);
    const int d = w * 16 + quad * 4 + r;        // V: C row = d
    Vt[((size_t)b * DD + d) * S_LEN + sb + ln] = f2bf(acc[2][r]);
  }
}

// ======================= Kernel 2: causal flash attention =======================
// 512 blocks x 256 thr (4/CU: LDS ~39.5 KB). Block = 32-row q-band; 4 waves
// take KV-64 tiles round-robin. Long bands dispatched FIRST (tail cut).
// No-running-max softmax (clamped). P round-trips LDS in fp32 (no write-side
// convert); packed cvt on readback. O/l partials combined via the same LDS
// (per-wave union: P region reused for O after the wave's loop ends).
#define PSTRW 76  // P row stride in f32 words: writes 2-way (free), b128 reads balanced

__global__ __launch_bounds__(256, 4) void attn_kernel(
    const short* __restrict__ Qb, const short* __restrict__ Kb,
    const short* __restrict__ Vt, float* __restrict__ out) {
  __shared__ float sbuf[4][32 * PSTRW];  // 38.9 KB: per-wave P (loop) / O partials (end)
  __shared__ float llds[4][32];

  const int tid  = threadIdx.x;
  const int w    = tid >> 6;
  const int lane = tid & 63;
  const int ln   = lane & 15;
  const int quad = lane >> 4;
  const int g    = blockIdx.x;
  const int b    = (g >> 1) & 3;                       // batch (XCD-pair locality)
  const int band = 127 - (((g >> 3) << 1) | (g & 1));  // long bands first
  const int qb   = band * 32;
  const int qg0  = b * S_LEN + qb;

  short8 aQ[2][2];
#pragma unroll
  for (int rfi = 0; rfi < 2; ++rfi)
#pragma unroll
    for (int h = 0; h < 2; ++h)
      aQ[rfi][h] = *(const short8*)(Qb + (size_t)(qg0 + rfi * 16 + ln) * DD + h * 32 + quad * 8);

  const short* Kbase = Kb + (size_t)b * S_LEN * DD;
  const short* Vbase = Vt + (size_t)b * DD * S_LEN;
  float* pw = &sbuf[w][0];

  const float4v zz = {0.f, 0.f, 0.f, 0.f};
  float4v o[2][4];
  float lp[2][4];
#pragma unroll
  for (int rfi = 0; rfi < 2; ++rfi)
#pragma unroll
    for (int d = 0; d < 4; ++d) { o[rfi][d] = zz; lp[rfi][d] = 0.f; }

  const int T = (qb + 95) >> 6;  // ceil((qb+32)/64)

  // preload K for tile it=w (kv0 <= 192, always in-bounds)
  short8 Kc[4][2], Kn[4][2];
#pragma unroll
  for (int c = 0; c < 4; ++c)
#pragma unroll
    for (int h = 0; h < 2; ++h)
      Kc[c][h] = *(const short8*)(Kbase + (size_t)(w * 64 + c * 16 + ln) * DD + h * 32 + quad * 8);

  for (int it = w; it < T; it += 4) {
    const int kv0 = it * 64;
    // V for this tile: consumed last, latency hidden behind QK/exp/P
    short8 Vc[4][2];
#pragma unroll
    for (int d = 0; d < 4; ++d)
#pragma unroll
      for (int h = 0; h < 2; ++h)
        Vc[d][h] = *(const short8*)(Vbase + (size_t)(d * 16 + ln) * S_LEN + kv0 + h * 32 + quad * 8);

    // S = Q K^T
    float4v s[2][4];
#pragma unroll
    for (int rfi = 0; rfi < 2; ++rfi)
#pragma unroll
      for (int c = 0; c < 4; ++c) {
        s[rfi][c] = MFMA16(aQ[rfi][0], Kc[c][0], zz);
        s[rfi][c] = MFMA16(aQ[rfi][1], Kc[c][1], s[rfi][c]);
      }

    // prefetch next K tile
    const int kvn = (it + 4 < T) ? (it + 4) * 64 : 0;
#pragma unroll
    for (int c = 0; c < 4; ++c)
#pragma unroll
      for (int h = 0; h < 2; ++h)
        Kn[c][h] = *(const short8*)(Kbase + (size_t)(kvn + c * 16 + ln) * DD + h * 32 + quad * 8);

    const bool needmask = (kv0 + 63) > qb;
#pragma unroll
    for (int rfi = 0; rfi < 2; ++rfi) {
      float p[4][4];
#pragma unroll
      for (int c = 0; c < 4; ++c)
#pragma unroll
        for (int r = 0; r < 4; ++r) {
          float e = exp2f(fminf(s[rfi][c][r] * SCL2, 43.0f));
          if (needmask && (kv0 + c * 16 + ln > qb + rfi * 16 + quad * 4 + r)) e = 0.f;
          p[c][r] = e;
        }
#pragma unroll
      for (int r = 0; r < 4; ++r)
        lp[rfi][r] += p[0][r] + p[1][r] + p[2][r] + p[3][r];
      // P (fp32) -> LDS, row-major [q][kv]
#pragma unroll
      for (int c = 0; c < 4; ++c)
#pragma unroll
        for (int r = 0; r < 4; ++r)
          pw[(rfi * 16 + quad * 4 + r) * PSTRW + c * 16 + ln] = p[c][r];
    }
    asm volatile("s_waitcnt lgkmcnt(0)" ::: "memory");  // wave-private LDS drain
    short8 aP[2][2];
#pragma unroll
    for (int rfi = 0; rfi < 2; ++rfi)
#pragma unroll
      for (int h = 0; h < 2; ++h) {
        const float4v lo = *(const float4v*)&pw[(rfi * 16 + ln) * PSTRW + h * 32 + quad * 8];
        const float4v hi = *(const float4v*)&pw[(rfi * 16 + ln) * PSTRW + h * 32 + quad * 8 + 4];
        aP[rfi][h] = cvt8(lo, hi);
      }
#pragma unroll
    for (int rfi = 0; rfi < 2; ++rfi)
#pragma unroll
      for (int d = 0; d < 4; ++d) {
        o[rfi][d] = MFMA16(aP[rfi][0], Vc[d][0], o[rfi][d]);
        o[rfi][d] = MFMA16(aP[rfi][1], Vc[d][1], o[rfi][d]);
      }
#pragma unroll
    for (int c = 0; c < 4; ++c)
#pragma unroll
      for (int h = 0; h < 2; ++h)
        Kc[c][h] = Kn[c][h];
  }

  // publish partials into this wave's sbuf region (own P region -> safe reuse)
#pragma unroll
  for (int rfi = 0; rfi < 2; ++rfi)
#pragma unroll
    for (int r = 0; r < 4; ++r) {
      float lr = lp[rfi][r];
      lr += __shfl_xor(lr, 1);
      lr += __shfl_xor(lr, 2);
      lr += __shfl_xor(lr, 4);
      lr += __shfl_xor(lr, 8);
      if (ln == 0) llds[w][rfi * 16 + quad * 4 + r] = lr;
#pragma unroll
      for (int d = 0; d < 4; ++d)
        pw[(rfi * 16 + quad * 4 + r) * 64 + d * 16 + ln] = o[rfi][d][r];
    }
  __syncthreads();

#pragma unroll
  for (int j = 0; j < 8; ++j) {
    const int idx = tid + j * 256;
    const int row = idx >> 6, col = idx & 63;
    const float sum = sbuf[0][row * 64 + col] + sbuf[1][row * 64 + col] +
                      sbuf[2][row * 64 + col] + sbuf[3][row * 64 + col];
    const float lt = llds[0][row] + llds[1][row] + llds[2][row] + llds[3][row];
    out[(size_t)(qg0 + row) * DD + col] = sum / lt;
  }
}

extern "C" void kernel_launch(void* const* d_in, const int* in_sizes, int n_in,
                              void* d_out, int out_size, void* d_ws, size_t ws_size,
                              hipStream_t stream) {
  const float* x  = (const float*)d_in[0];
  const float* Wq = (const float*)d_in[1];
  const float* Wk = (const float*)d_in[2];
  const float* Wv = (const float*)d_in[3];

  short* Qb  = (short*)d_ws;                       // 2 MB
  short* Kb  = Qb + (size_t)NROWS * DD;            // 2 MB
  short* Vt  = Kb + (size_t)NROWS * DD;            // 2 MB  [b][d][s]
  short* Wb2 = Vt + (size_t)NROWS * DD;            // 384 KB panels

  wcvt_kernel<<<dim3(96), dim3(256), 0, stream>>>(Wq, Wk, Wv, Wb2);
  qkv_kernel<<<dim3(NROWS / 16), dim3(256), 0, stream>>>(x, Wb2, Qb, Kb, Vt);
  attn_kernel<<<dim3(NBATCH * 128), dim3(256), 0, stream>>>(Qb, Kb, Vt, (float*)d_out);
}

// Round 5
// 181.454 us; speedup vs baseline: 1.4033x; 1.4033x over previous
//
#include <hip/hip_runtime.h>
#include <hip/hip_bf16.h>
#include <stdint.h>

typedef __attribute__((ext_vector_type(8))) short  short8;   // 8 bf16 (4 VGPR) MFMA A/B frag
typedef __attribute__((ext_vector_type(4))) short  short4v;
typedef __attribute__((ext_vector_type(4))) float  float4v;  // MFMA C/D frag

#define MFMA16(a, b, c) __builtin_amdgcn_mfma_f32_16x16x32_bf16((a), (b), (c), 0, 0, 0)

#define S_LEN  4096
#define NBATCH 4
#define EMB    1024
#define DD     64
#define NROWS  (NBATCH * S_LEN)  // 16384
#define SCL2   0.1803368801111204f  // (1/sqrt(64)) * log2(e), folded into Wq at wcvt

static __device__ __forceinline__ short f2bf(float f) {
  uint32_t u = __float_as_uint(f);
  return (short)((u + 0x7FFFu + ((u >> 16) & 1u)) >> 16);
}
static __device__ __forceinline__ unsigned pk2(float a, float b) {
  union { __hip_bfloat162 h; unsigned u; } z;
  z.h = __float22bfloat162_rn(make_float2(a, b));
  return z.u;
}
static __device__ __forceinline__ short8 cvt8(float4v a, float4v b) {
  union { unsigned u[4]; short8 s; } z;
  z.u[0] = pk2(a[0], a[1]); z.u[1] = pk2(a[2], a[3]);
  z.u[2] = pk2(b[0], b[1]); z.u[3] = pk2(b[2], b[3]);
  return z.s;
}

// ============ Kernel 0: W fp32 -> bf16, reordered into 32-k panels ============
// Wb2 layout: [32 panels][192 rows][32 k] bf16; rows 0-63=Wq (pre-scaled by
// SCL2 so attention scores arrive in log2 domain), 64-127=Wk, 128-191=Wv.
__global__ void wcvt_kernel(const float* __restrict__ Wq, const float* __restrict__ Wk,
                            const float* __restrict__ Wv, short* __restrict__ Wb2) {
  const int t   = blockIdx.x * 256 + threadIdx.x;  // 0..24575, 8 elems each
  const int row = t >> 7;
  const int k   = (t & 127) * 8;
  const float* src = (row < 64) ? (Wq + (size_t)row * EMB)
                   : (row < 128) ? (Wk + (size_t)(row - 64) * EMB)
                                 : (Wv + (size_t)(row - 128) * EMB);
  const float sc = (row < 64) ? SCL2 : 1.0f;
  float4v a = *(const float4v*)(src + k);
  float4v b = *(const float4v*)(src + k + 4);
#pragma unroll
  for (int i = 0; i < 4; ++i) { a[i] *= sc; b[i] *= sc; }
  *(short8*)(Wb2 + (((k >> 5) * 192 + row) << 5) + (k & 31)) = cvt8(a, b);
}

// ======================= Kernel 1: QKV projection GEMM =======================
// Barrier-free: 1024 blocks x 4 waves, 16 x-rows per block. Wave w owns frags
// {Q_w, K_w, V_w}; V operand-swapped -> transposed output Vt[b][d][s].
// 2-deep register prefetch to cover HBM latency on the x stream.
__global__ __launch_bounds__(256, 4) void qkv_kernel(
    const float* __restrict__ x, const short* __restrict__ Wb2,
    short* __restrict__ Qb, short* __restrict__ Kb, short* __restrict__ Vt) {
  const int tid  = threadIdx.x;
  const int w    = tid >> 6;
  const int lane = tid & 63;
  const int ln   = lane & 15;
  const int quad = lane >> 4;
  const int m0   = blockIdx.x * 16;

  const float* xp = x + (size_t)(m0 + ln) * EMB + quad * 8;
  const short* wp[3];
#pragma unroll
  for (int i = 0; i < 3; ++i)
    wp[i] = Wb2 + (size_t)(i * 64 + w * 16 + ln) * 32 + quad * 8;  // panel 0 row

  const float4v zz = {0.f, 0.f, 0.f, 0.f};
  float4v acc[3] = {zz, zz, zz};

  // 2-deep preload (steps 0,1)
  float4v a0[2], a1[2];
  short8 bpf[2][3];
#pragma unroll
  for (int s = 0; s < 2; ++s) {
    a0[s] = *(const float4v*)(xp + s * 32);
    a1[s] = *(const float4v*)(xp + s * 32 + 4);
#pragma unroll
    for (int i = 0; i < 3; ++i)
      bpf[s][i] = *(const short8*)(wp[i] + (size_t)s * 6144);
  }

  for (int s = 0; s < 32; ++s) {
    const int cur = s & 1;
    const short8 xf = cvt8(a0[cur], a1[cur]);
    short8 bf[3];
#pragma unroll
    for (int i = 0; i < 3; ++i) bf[i] = bpf[cur][i];
    const int sn = (s + 2 < 32) ? s + 2 : s;  // harmless re-load at tail
    a0[cur] = *(const float4v*)(xp + sn * 32);
    a1[cur] = *(const float4v*)(xp + sn * 32 + 4);
#pragma unroll
    for (int i = 0; i < 3; ++i)
      bpf[cur][i] = *(const short8*)(wp[i] + (size_t)sn * 6144);
    acc[0] = MFMA16(xf, bf[0], acc[0]);   // Q (pre-scaled)
    acc[1] = MFMA16(xf, bf[1], acc[1]);   // K
    acc[2] = MFMA16(bf[2], xf, acc[2]);   // V, swapped -> transposed output
  }

  const int b  = m0 >> 12;
  const int sb = m0 & (S_LEN - 1);
#pragma unroll
  for (int r = 0; r < 4; ++r) {
    const int row = m0 + quad * 4 + r;          // Q/K: C row = x-row
    Qb[(size_t)row * DD + w * 16 + ln] = f2bf(acc[0][r]);
    Kb[(size_t)row * DD + w * 16 + ln] = f2bf(acc[1][r]);
    const int d = w * 16 + quad * 4 + r;        // V: C row = d
    Vt[((size_t)b * DD + d) * S_LEN + sb + ln] = f2bf(acc[2][r]);
  }
}

// ======================= Kernel 2: causal flash attention =======================
// 256 blocks x 512 thr (1/CU, 8 waves). Block = band PAIR (j, 127-j): total
// tiles T(j)+T(127-j) ~ 66.5 = UNIFORM -> no tail. Two sequential phases, each
// with its own LDS-combine epilogue (single accumulator set -> no spills).
// Waves split a phase's KV tiles round-robin (it += 8). No-running-max softmax
// (clamped; scores pre-scaled via Wq). P round-trips per-wave LDS in fp32.
#define PSTRW 76  // P row stride in f32 words: writes 2-way (free), reads balanced

__global__ __launch_bounds__(512, 2) void attn_kernel(
    const short* __restrict__ Qb, const short* __restrict__ Kb,
    const short* __restrict__ Vt, float* __restrict__ out) {
  __shared__ float sbuf[8][32 * PSTRW];  // 77.8 KB: per-wave P (loop) / O partials (epilogue)
  __shared__ float llds[8][32];

  const int tid  = threadIdx.x;
  const int w    = tid >> 6;
  const int lane = tid & 63;
  const int ln   = lane & 15;
  const int quad = lane >> 4;
  const int g    = blockIdx.x;
  const int b    = g & 3;          // batch
  const int j    = g >> 2;         // pair index 0..63
  const short* Kbase = Kb + (size_t)b * S_LEN * DD;
  const short* Vbase = Vt + (size_t)b * DD * S_LEN;
  float* pw = &sbuf[w][0];
  const float4v zz = {0.f, 0.f, 0.f, 0.f};

  for (int ph = 0; ph < 2; ++ph) {
    const int band = ph ? (127 - j) : j;
    const int qb   = band * 32;
    const int qg0  = b * S_LEN + qb;

    short8 aQ[2][2];
#pragma unroll
    for (int rfi = 0; rfi < 2; ++rfi)
#pragma unroll
      for (int h = 0; h < 2; ++h)
        aQ[rfi][h] = *(const short8*)(Qb + (size_t)(qg0 + rfi * 16 + ln) * DD + h * 32 + quad * 8);

    float4v o[2][4];
    float lp[2][4];
#pragma unroll
    for (int rfi = 0; rfi < 2; ++rfi)
#pragma unroll
      for (int d = 0; d < 4; ++d) { o[rfi][d] = zz; lp[rfi][d] = 0.f; }

    const int T = (qb + 95) >> 6;  // ceil((qb+32)/64)

    // preload K for tile it=w (kv0 = w*64 <= 448, always in-bounds)
    short8 Kc[4][2], Kn[4][2];
#pragma unroll
    for (int c = 0; c < 4; ++c)
#pragma unroll
      for (int h = 0; h < 2; ++h)
        Kc[c][h] = *(const short8*)(Kbase + (size_t)(w * 64 + c * 16 + ln) * DD + h * 32 + quad * 8);

    for (int it = w; it < T; it += 8) {
      const int kv0 = it * 64;
      // V for this tile: consumed last, latency hidden behind QK/exp/P
      short8 Vc[4][2];
#pragma unroll
      for (int d = 0; d < 4; ++d)
#pragma unroll
        for (int h = 0; h < 2; ++h)
          Vc[d][h] = *(const short8*)(Vbase + (size_t)(d * 16 + ln) * S_LEN + kv0 + h * 32 + quad * 8);

      // S = Q K^T (already in log2 domain)
      float4v s[2][4];
#pragma unroll
      for (int rfi = 0; rfi < 2; ++rfi)
#pragma unroll
        for (int c = 0; c < 4; ++c) {
          s[rfi][c] = MFMA16(aQ[rfi][0], Kc[c][0], zz);
          s[rfi][c] = MFMA16(aQ[rfi][1], Kc[c][1], s[rfi][c]);
        }

      // prefetch next K tile
      const int kvn = (it + 8 < T) ? (it + 8) * 64 : 0;
#pragma unroll
      for (int c = 0; c < 4; ++c)
#pragma unroll
        for (int h = 0; h < 2; ++h)
          Kn[c][h] = *(const short8*)(Kbase + (size_t)(kvn + c * 16 + ln) * DD + h * 32 + quad * 8);

      const bool needmask = (kv0 + 63) > qb;
#pragma unroll
      for (int rfi = 0; rfi < 2; ++rfi) {
        float p[4][4];
#pragma unroll
        for (int c = 0; c < 4; ++c)
#pragma unroll
          for (int r = 0; r < 4; ++r) {
            float e = exp2f(fminf(s[rfi][c][r], 60.0f));
            if (needmask && (kv0 + c * 16 + ln > qb + rfi * 16 + quad * 4 + r)) e = 0.f;
            p[c][r] = e;
          }
#pragma unroll
        for (int r = 0; r < 4; ++r)
          lp[rfi][r] += p[0][r] + p[1][r] + p[2][r] + p[3][r];
#pragma unroll
        for (int c = 0; c < 4; ++c)
#pragma unroll
          for (int r = 0; r < 4; ++r)
            pw[(rfi * 16 + quad * 4 + r) * PSTRW + c * 16 + ln] = p[c][r];
      }
      asm volatile("s_waitcnt lgkmcnt(0)" ::: "memory");  // wave-private LDS drain
      short8 aP[2][2];
#pragma unroll
      for (int rfi = 0; rfi < 2; ++rfi)
#pragma unroll
        for (int h = 0; h < 2; ++h) {
          const float4v lo = *(const float4v*)&pw[(rfi * 16 + ln) * PSTRW + h * 32 + quad * 8];
          const float4v hi = *(const float4v*)&pw[(rfi * 16 + ln) * PSTRW + h * 32 + quad * 8 + 4];
          aP[rfi][h] = cvt8(lo, hi);
        }
#pragma unroll
      for (int rfi = 0; rfi < 2; ++rfi)
#pragma unroll
        for (int d = 0; d < 4; ++d) {
          o[rfi][d] = MFMA16(aP[rfi][0], Vc[d][0], o[rfi][d]);
          o[rfi][d] = MFMA16(aP[rfi][1], Vc[d][1], o[rfi][d]);
        }
#pragma unroll
      for (int c = 0; c < 4; ++c)
#pragma unroll
        for (int h = 0; h < 2; ++h)
          Kc[c][h] = Kn[c][h];
    }

    // publish partials into this wave's sbuf region (own P region -> safe reuse)
#pragma unroll
    for (int rfi = 0; rfi < 2; ++rfi)
#pragma unroll
      for (int r = 0; r < 4; ++r) {
        float lr = lp[rfi][r];
        lr += __shfl_xor(lr, 1);
        lr += __shfl_xor(lr, 2);
        lr += __shfl_xor(lr, 4);
        lr += __shfl_xor(lr, 8);
        if (ln == 0) llds[w][rfi * 16 + quad * 4 + r] = lr;
#pragma unroll
        for (int d = 0; d < 4; ++d)
          pw[(rfi * 16 + quad * 4 + r) * 64 + d * 16 + ln] = o[rfi][d][r];
      }
    __syncthreads();

#pragma unroll
    for (int jj = 0; jj < 4; ++jj) {
      const int idx = tid + jj * 512;
      const int row = idx >> 6, col = idx & 63;
      float sum = 0.f, lt = 0.f;
#pragma unroll
      for (int wi = 0; wi < 8; ++wi) {
        sum += sbuf[wi][row * 64 + col];
        lt  += llds[wi][row];
      }
      out[(size_t)(qg0 + row) * DD + col] = sum / lt;
    }
    __syncthreads();  // sbuf reused as P in next phase
  }
}

extern "C" void kernel_launch(void* const* d_in, const int* in_sizes, int n_in,
                              void* d_out, int out_size, void* d_ws, size_t ws_size,
                              hipStream_t stream) {
  const float* x  = (const float*)d_in[0];
  const float* Wq = (const float*)d_in[1];
  const float* Wk = (const float*)d_in[2];
  const float* Wv = (const float*)d_in[3];

  short* Qb  = (short*)d_ws;                       // 2 MB
  short* Kb  = Qb + (size_t)NROWS * DD;            // 2 MB
  short* Vt  = Kb + (size_t)NROWS * DD;            // 2 MB  [b][d][s]
  short* Wb2 = Vt + (size_t)NROWS * DD;            // 384 KB panels

  wcvt_kernel<<<dim3(96), dim3(256), 0, stream>>>(Wq, Wk, Wv, Wb2);
  qkv_kernel<<<dim3(NROWS / 16), dim3(256), 0, stream>>>(x, Wb2, Qb, Kb, Vt);
  attn_kernel<<<dim3(NBATCH * 64), dim3(512), 0, stream>>>(Qb, Kb, Vt, (float*)d_out);
}

// Round 6
// 161.544 us; speedup vs baseline: 1.5763x; 1.1232x over previous
//
#include <hip/hip_runtime.h>
#include <hip/hip_bf16.h>
#include <stdint.h>

typedef __attribute__((ext_vector_type(8))) short  short8;   // 8 bf16 (4 VGPR) MFMA A/B frag
typedef __attribute__((ext_vector_type(4))) short  short4v;
typedef __attribute__((ext_vector_type(4))) float  float4v;  // MFMA C/D frag

#define MFMA16(a, b, c) __builtin_amdgcn_mfma_f32_16x16x32_bf16((a), (b), (c), 0, 0, 0)

#define S_LEN  4096
#define NBATCH 4
#define EMB    1024
#define DD     64
#define NROWS  (NBATCH * S_LEN)  // 16384
#define SCL2   0.1803368801111204f  // (1/sqrt(64)) * log2(e), folded into Wq at wcvt

#define AS1 const __attribute__((address_space(1))) unsigned int*
#define AS3 __attribute__((address_space(3))) unsigned int*

static __device__ __forceinline__ short f2bf(float f) {
  uint32_t u = __float_as_uint(f);
  return (short)((u + 0x7FFFu + ((u >> 16) & 1u)) >> 16);
}
static __device__ __forceinline__ unsigned pk2(float a, float b) {
  union { __hip_bfloat162 h; unsigned u; } z;
  z.h = __float22bfloat162_rn(make_float2(a, b));
  return z.u;
}
static __device__ __forceinline__ short8 cvt8(float4v a, float4v b) {
  union { unsigned u[4]; short8 s; } z;
  z.u[0] = pk2(a[0], a[1]); z.u[1] = pk2(a[2], a[3]);
  z.u[2] = pk2(b[0], b[1]); z.u[3] = pk2(b[2], b[3]);
  return z.s;
}

// ============ Kernel 0: W fp32 -> bf16, reordered into 32-k panels ============
// Wb2 layout: [32 panels][192 rows][32 k] bf16; rows 0-63=Wq (pre-scaled by
// SCL2 -> scores arrive in log2 domain), 64-127=Wk, 128-191=Wv.
__global__ void wcvt_kernel(const float* __restrict__ Wq, const float* __restrict__ Wk,
                            const float* __restrict__ Wv, short* __restrict__ Wb2) {
  const int t   = blockIdx.x * 256 + threadIdx.x;  // 0..24575, 8 elems each
  const int row = t >> 7;
  const int k   = (t & 127) * 8;
  const float* src = (row < 64) ? (Wq + (size_t)row * EMB)
                   : (row < 128) ? (Wk + (size_t)(row - 64) * EMB)
                                 : (Wv + (size_t)(row - 128) * EMB);
  const float sc = (row < 64) ? SCL2 : 1.0f;
  float4v a = *(const float4v*)(src + k);
  float4v b = *(const float4v*)(src + k + 4);
#pragma unroll
  for (int i = 0; i < 4; ++i) { a[i] *= sc; b[i] *= sc; }
  *(short8*)(Wb2 + (((k >> 5) * 192 + row) << 5) + (k & 31)) = cvt8(a, b);
}

// ======================= Kernel 1: QKV projection GEMM =======================
// m97-style async GEMM: 512 blocks x 256 thr (2/CU), M-tile 32, BK=64.
// Both x (fp32) and W panels (bf16) staged via global_load_lds width=16 into
// double-buffered LDS; one barrier/step, next-stage DMA issued AFTER the
// barrier so it overlaps compute (next barrier's vmcnt(0) drains it).
// LDS layouts are DMA lane-order (slot = one wave-instr's 1 KB, lane i at
// i*16B) -- no padding (m104 constraint); frag reads derived to match.
// Wave w = (row-half w&1, col-half w>>1); col-half 0: Q0-3,K0-1; col-half 1:
// K2-3,V0-3 (V operand-swapped -> transposed out Vt[b][d][s]).
__global__ __launch_bounds__(256, 2) void qkv_kernel(
    const float* __restrict__ x, const short* __restrict__ Wb2,
    short* __restrict__ Qb, short* __restrict__ Kb, short* __restrict__ Vt) {
  __shared__ float As[2][2048];   // 2 x 8 KB  (32 rows x 64 k fp32, slot order)
  __shared__ short Bs[2][12288];  // 2 x 24 KB (2 panels x 192 x 32 bf16, identity)

  const int tid  = threadIdx.x;
  const int w    = tid >> 6;
  const int lane = tid & 63;
  const int ln   = lane & 15;
  const int quad = lane >> 4;
  const int m0   = blockIdx.x * 32;
  const int wr   = w & 1;
  const int wc   = w >> 1;

  // --- staging source pointers (per-lane) ---
  // A slots t=2w,2w+1: slot t lane i holds x[row m0+((t>>2)<<4)+(i>>2)][k-chunk (t&3)*4+(i&3)]
  const int tA0 = 2 * w, tA1 = 2 * w + 1;
  const float* xA0 = x + (size_t)(m0 + ((tA0 >> 2) << 4) + (lane >> 2)) * EMB
                       + ((tA0 & 3) * 4 + (lane & 3)) * 4;
  const float* xA1 = x + (size_t)(m0 + ((tA1 >> 2) << 4) + (lane >> 2)) * EMB
                       + ((tA1 & 3) * 4 + (lane & 3)) * 4;
  // B slots u=6w..6w+5: identity copy of the step's 24 KB panel pair
  const short* wB = Wb2 + (size_t)(6 * w) * 512 + lane * 8;

#define STAGE(S, BUF) do {                                                      \
    __builtin_amdgcn_global_load_lds((AS1)(xA0 + (S) * 64),                     \
        (AS3)&As[BUF][tA0 * 256], 16, 0, 0);                                    \
    __builtin_amdgcn_global_load_lds((AS1)(xA1 + (S) * 64),                     \
        (AS3)&As[BUF][tA1 * 256], 16, 0, 0);                                    \
    _Pragma("unroll")                                                           \
    for (int j = 0; j < 6; ++j)                                                 \
      __builtin_amdgcn_global_load_lds((AS1)(wB + (size_t)(S) * 12288 + j * 512),\
          (AS3)&Bs[BUF][(6 * w + j) * 512], 16, 0, 0);                          \
  } while (0)

  const float4v zz = {0.f, 0.f, 0.f, 0.f};
  float4v acc[6] = {zz, zz, zz, zz, zz, zz};

  STAGE(0, 0);
  int buf = 0;
  for (int s = 0; s < 16; ++s) {
    __syncthreads();                       // drains this buf's DMA (vmcnt 0)
    if (s + 1 < 16) STAGE(s + 1, buf ^ 1); // overlaps with compute below
    // A-frags: rows wr*16+ln, k-halves h: floats at slot-order address
    short8 aF[2];
#pragma unroll
    for (int h = 0; h < 2; ++h) {
      const int ai = (wr * 4 + 2 * h + (quad >> 1)) * 256 + (ln * 4 + (quad & 1) * 2) * 4;
      const float4v lo = *(const float4v*)&As[buf][ai];
      const float4v hi = *(const float4v*)&As[buf][ai + 4];
      aF[h] = cvt8(lo, hi);
    }
#pragma unroll
    for (int f = 0; f < 6; ++f) {
      const int cf = wc * 6 + f;
      const short8 b0 = *(const short8*)&Bs[buf][(cf * 16 + ln) * 32 + quad * 8];
      const short8 b1 = *(const short8*)&Bs[buf][6144 + (cf * 16 + ln) * 32 + quad * 8];
      if (wc == 0 || f < 2) {
        acc[f] = MFMA16(aF[0], b0, acc[f]);
        acc[f] = MFMA16(aF[1], b1, acc[f]);
      } else {  // V frags: operand swap -> transposed output
        acc[f] = MFMA16(b0, aF[0], acc[f]);
        acc[f] = MFMA16(b1, aF[1], acc[f]);
      }
    }
    buf ^= 1;
  }
#undef STAGE

  const int b  = m0 >> 12;
  const int sb = m0 & (S_LEN - 1);
  if (wc == 0) {
#pragma unroll
    for (int f = 0; f < 6; ++f)
#pragma unroll
      for (int r = 0; r < 4; ++r) {
        const int row = m0 + wr * 16 + quad * 4 + r;
        if (f < 4) Qb[(size_t)row * DD + f * 16 + ln] = f2bf(acc[f][r]);
        else       Kb[(size_t)row * DD + (f - 4) * 16 + ln] = f2bf(acc[f][r]);
      }
  } else {
#pragma unroll
    for (int f = 0; f < 2; ++f)
#pragma unroll
      for (int r = 0; r < 4; ++r) {
        const int row = m0 + wr * 16 + quad * 4 + r;
        Kb[(size_t)row * DD + 32 + f * 16 + ln] = f2bf(acc[f][r]);
      }
#pragma unroll
    for (int f = 2; f < 6; ++f)
#pragma unroll
      for (int r = 0; r < 4; ++r) {
        const int d = (f - 2) * 16 + quad * 4 + r;
        Vt[((size_t)b * DD + d) * S_LEN + sb + wr * 16 + ln] = f2bf(acc[f][r]);
      }
  }
}

// ======================= Kernel 2: causal flash attention =======================
// (unchanged from round 5 -- band-pairing removed the causal tail)
#define PSTRW 76

__global__ __launch_bounds__(512, 2) void attn_kernel(
    const short* __restrict__ Qb, const short* __restrict__ Kb,
    const short* __restrict__ Vt, float* __restrict__ out) {
  __shared__ float sbuf[8][32 * PSTRW];
  __shared__ float llds[8][32];

  const int tid  = threadIdx.x;
  const int w    = tid >> 6;
  const int lane = tid & 63;
  const int ln   = lane & 15;
  const int quad = lane >> 4;
  const int g    = blockIdx.x;
  const int b    = g & 3;
  const int j    = g >> 2;
  const short* Kbase = Kb + (size_t)b * S_LEN * DD;
  const short* Vbase = Vt + (size_t)b * DD * S_LEN;
  float* pw = &sbuf[w][0];
  const float4v zz = {0.f, 0.f, 0.f, 0.f};

  for (int ph = 0; ph < 2; ++ph) {
    const int band = ph ? (127 - j) : j;
    const int qb   = band * 32;
    const int qg0  = b * S_LEN + qb;

    short8 aQ[2][2];
#pragma unroll
    for (int rfi = 0; rfi < 2; ++rfi)
#pragma unroll
      for (int h = 0; h < 2; ++h)
        aQ[rfi][h] = *(const short8*)(Qb + (size_t)(qg0 + rfi * 16 + ln) * DD + h * 32 + quad * 8);

    float4v o[2][4];
    float lp[2][4];
#pragma unroll
    for (int rfi = 0; rfi < 2; ++rfi)
#pragma unroll
      for (int d = 0; d < 4; ++d) { o[rfi][d] = zz; lp[rfi][d] = 0.f; }

    const int T = (qb + 95) >> 6;

    short8 Kc[4][2], Kn[4][2];
#pragma unroll
    for (int c = 0; c < 4; ++c)
#pragma unroll
      for (int h = 0; h < 2; ++h)
        Kc[c][h] = *(const short8*)(Kbase + (size_t)(w * 64 + c * 16 + ln) * DD + h * 32 + quad * 8);

    for (int it = w; it < T; it += 8) {
      const int kv0 = it * 64;
      short8 Vc[4][2];
#pragma unroll
      for (int d = 0; d < 4; ++d)
#pragma unroll
        for (int h = 0; h < 2; ++h)
          Vc[d][h] = *(const short8*)(Vbase + (size_t)(d * 16 + ln) * S_LEN + kv0 + h * 32 + quad * 8);

      float4v s[2][4];
#pragma unroll
      for (int rfi = 0; rfi < 2; ++rfi)
#pragma unroll
        for (int c = 0; c < 4; ++c) {
          s[rfi][c] = MFMA16(aQ[rfi][0], Kc[c][0], zz);
          s[rfi][c] = MFMA16(aQ[rfi][1], Kc[c][1], s[rfi][c]);
        }

      const int kvn = (it + 8 < T) ? (it + 8) * 64 : 0;
#pragma unroll
      for (int c = 0; c < 4; ++c)
#pragma unroll
        for (int h = 0; h < 2; ++h)
          Kn[c][h] = *(const short8*)(Kbase + (size_t)(kvn + c * 16 + ln) * DD + h * 32 + quad * 8);

      const bool needmask = (kv0 + 63) > qb;
#pragma unroll
      for (int rfi = 0; rfi < 2; ++rfi) {
        float p[4][4];
#pragma unroll
        for (int c = 0; c < 4; ++c)
#pragma unroll
          for (int r = 0; r < 4; ++r) {
            float e = exp2f(fminf(s[rfi][c][r], 60.0f));
            if (needmask && (kv0 + c * 16 + ln > qb + rfi * 16 + quad * 4 + r)) e = 0.f;
            p[c][r] = e;
          }
#pragma unroll
        for (int r = 0; r < 4; ++r)
          lp[rfi][r] += p[0][r] + p[1][r] + p[2][r] + p[3][r];
#pragma unroll
        for (int c = 0; c < 4; ++c)
#pragma unroll
          for (int r = 0; r < 4; ++r)
            pw[(rfi * 16 + quad * 4 + r) * PSTRW + c * 16 + ln] = p[c][r];
      }
      asm volatile("s_waitcnt lgkmcnt(0)" ::: "memory");
      short8 aP[2][2];
#pragma unroll
      for (int rfi = 0; rfi < 2; ++rfi)
#pragma unroll
        for (int h = 0; h < 2; ++h) {
          const float4v lo = *(const float4v*)&pw[(rfi * 16 + ln) * PSTRW + h * 32 + quad * 8];
          const float4v hi = *(const float4v*)&pw[(rfi * 16 + ln) * PSTRW + h * 32 + quad * 8 + 4];
          aP[rfi][h] = cvt8(lo, hi);
        }
#pragma unroll
      for (int rfi = 0; rfi < 2; ++rfi)
#pragma unroll
        for (int d = 0; d < 4; ++d) {
          o[rfi][d] = MFMA16(aP[rfi][0], Vc[d][0], o[rfi][d]);
          o[rfi][d] = MFMA16(aP[rfi][1], Vc[d][1], o[rfi][d]);
        }
#pragma unroll
      for (int c = 0; c < 4; ++c)
#pragma unroll
        for (int h = 0; h < 2; ++h)
          Kc[c][h] = Kn[c][h];
    }

#pragma unroll
    for (int rfi = 0; rfi < 2; ++rfi)
#pragma unroll
      for (int r = 0; r < 4; ++r) {
        float lr = lp[rfi][r];
        lr += __shfl_xor(lr, 1);
        lr += __shfl_xor(lr, 2);
        lr += __shfl_xor(lr, 4);
        lr += __shfl_xor(lr, 8);
        if (ln == 0) llds[w][rfi * 16 + quad * 4 + r] = lr;
#pragma unroll
        for (int d = 0; d < 4; ++d)
          pw[(rfi * 16 + quad * 4 + r) * 64 + d * 16 + ln] = o[rfi][d][r];
      }
    __syncthreads();

#pragma unroll
    for (int jj = 0; jj < 4; ++jj) {
      const int idx = tid + jj * 512;
      const int row = idx >> 6, col = idx & 63;
      float sum = 0.f, lt = 0.f;
#pragma unroll
      for (int wi = 0; wi < 8; ++wi) {
        sum += sbuf[wi][row * 64 + col];
        lt  += llds[wi][row];
      }
      out[(size_t)(qg0 + row) * DD + col] = sum / lt;
    }
    __syncthreads();
  }
}

extern "C" void kernel_launch(void* const* d_in, const int* in_sizes, int n_in,
                              void* d_out, int out_size, void* d_ws, size_t ws_size,
                              hipStream_t stream) {
  const float* x  = (const float*)d_in[0];
  const float* Wq = (const float*)d_in[1];
  const float* Wk = (const float*)d_in[2];
  const float* Wv = (const float*)d_in[3];

  short* Qb  = (short*)d_ws;                       // 2 MB
  short* Kb  = Qb + (size_t)NROWS * DD;            // 2 MB
  short* Vt  = Kb + (size_t)NROWS * DD;            // 2 MB  [b][d][s]
  short* Wb2 = Vt + (size_t)NROWS * DD;            // 384 KB panels

  wcvt_kernel<<<dim3(96), dim3(256), 0, stream>>>(Wq, Wk, Wv, Wb2);
  qkv_kernel<<<dim3(NROWS / 32), dim3(256), 0, stream>>>(x, Wb2, Qb, Kb, Vt);
  attn_kernel<<<dim3(NBATCH * 64), dim3(512), 0, stream>>>(Qb, Kb, Vt, (float*)d_out);
}

// Round 7
// 161.195 us; speedup vs baseline: 1.5797x; 1.0022x over previous
//
#include <hip/hip_runtime.h>
#include <hip/hip_bf16.h>
#include <stdint.h>

typedef __attribute__((ext_vector_type(8))) short  short8;   // 8 bf16 (4 VGPR) MFMA A/B frag
typedef __attribute__((ext_vector_type(4))) short  short4v;
typedef __attribute__((ext_vector_type(4))) float  float4v;  // MFMA C/D frag

#define MFMA16(a, b, c) __builtin_amdgcn_mfma_f32_16x16x32_bf16((a), (b), (c), 0, 0, 0)

#define S_LEN  4096
#define NBATCH 4
#define EMB    1024
#define DD     64
#define NROWS  (NBATCH * S_LEN)  // 16384
#define SCL2   0.1803368801111204f  // (1/sqrt(64)) * log2(e), folded into Wq at wcvt

#define AS1 const __attribute__((address_space(1))) unsigned int*
#define AS3 __attribute__((address_space(3))) unsigned int*

static __device__ __forceinline__ short f2bf(float f) {
  uint32_t u = __float_as_uint(f);
  return (short)((u + 0x7FFFu + ((u >> 16) & 1u)) >> 16);
}
static __device__ __forceinline__ unsigned pk2(float a, float b) {
  union { __hip_bfloat162 h; unsigned u; } z;
  z.h = __float22bfloat162_rn(make_float2(a, b));
  return z.u;
}
static __device__ __forceinline__ short8 cvt8(float4v a, float4v b) {
  union { unsigned u[4]; short8 s; } z;
  z.u[0] = pk2(a[0], a[1]); z.u[1] = pk2(a[2], a[3]);
  z.u[2] = pk2(b[0], b[1]); z.u[3] = pk2(b[2], b[3]);
  return z.s;
}

// ============ Kernel 0: W fp32 -> bf16, reordered into 32-k panels ============
// Wb2 layout: [32 panels][192 rows][32 k] bf16; rows 0-63=Wq (pre-scaled by
// SCL2 -> scores arrive in log2 domain), 64-127=Wk, 128-191=Wv.
__global__ void wcvt_kernel(const float* __restrict__ Wq, const float* __restrict__ Wk,
                            const float* __restrict__ Wv, short* __restrict__ Wb2) {
  const int t   = blockIdx.x * 256 + threadIdx.x;  // 0..24575, 8 elems each
  const int row = t >> 7;
  const int k   = (t & 127) * 8;
  const float* src = (row < 64) ? (Wq + (size_t)row * EMB)
                   : (row < 128) ? (Wk + (size_t)(row - 64) * EMB)
                                 : (Wv + (size_t)(row - 128) * EMB);
  const float sc = (row < 64) ? SCL2 : 1.0f;
  float4v a = *(const float4v*)(src + k);
  float4v b = *(const float4v*)(src + k + 4);
#pragma unroll
  for (int i = 0; i < 4; ++i) { a[i] *= sc; b[i] *= sc; }
  *(short8*)(Wb2 + (((k >> 5) * 192 + row) << 5) + (k & 31)) = cvt8(a, b);
}

// ======================= Kernel 1: QKV projection GEMM =======================
// m97-style async GEMM: 512 blocks x 256 thr (2/CU), M-tile 32, BK=64.
// Both x (fp32) and W panels (bf16) staged via global_load_lds width=16 into
// double-buffered LDS; one barrier/step, next-stage DMA issued AFTER the
// barrier so it overlaps compute. (unchanged from round 6)
__global__ __launch_bounds__(256, 2) void qkv_kernel(
    const float* __restrict__ x, const short* __restrict__ Wb2,
    short* __restrict__ Qb, short* __restrict__ Kb, short* __restrict__ Vt) {
  __shared__ float As[2][2048];   // 2 x 8 KB  (32 rows x 64 k fp32, slot order)
  __shared__ short Bs[2][12288];  // 2 x 24 KB (2 panels x 192 x 32 bf16, identity)

  const int tid  = threadIdx.x;
  const int w    = tid >> 6;
  const int lane = tid & 63;
  const int ln   = lane & 15;
  const int quad = lane >> 4;
  const int m0   = blockIdx.x * 32;
  const int wr   = w & 1;
  const int wc   = w >> 1;

  const int tA0 = 2 * w, tA1 = 2 * w + 1;
  const float* xA0 = x + (size_t)(m0 + ((tA0 >> 2) << 4) + (lane >> 2)) * EMB
                       + ((tA0 & 3) * 4 + (lane & 3)) * 4;
  const float* xA1 = x + (size_t)(m0 + ((tA1 >> 2) << 4) + (lane >> 2)) * EMB
                       + ((tA1 & 3) * 4 + (lane & 3)) * 4;
  const short* wB = Wb2 + (size_t)(6 * w) * 512 + lane * 8;

#define STAGE(S, BUF) do {                                                      \
    __builtin_amdgcn_global_load_lds((AS1)(xA0 + (S) * 64),                     \
        (AS3)&As[BUF][tA0 * 256], 16, 0, 0);                                    \
    __builtin_amdgcn_global_load_lds((AS1)(xA1 + (S) * 64),                     \
        (AS3)&As[BUF][tA1 * 256], 16, 0, 0);                                    \
    _Pragma("unroll")                                                           \
    for (int j = 0; j < 6; ++j)                                                 \
      __builtin_amdgcn_global_load_lds((AS1)(wB + (size_t)(S) * 12288 + j * 512),\
          (AS3)&Bs[BUF][(6 * w + j) * 512], 16, 0, 0);                          \
  } while (0)

  const float4v zz = {0.f, 0.f, 0.f, 0.f};
  float4v acc[6] = {zz, zz, zz, zz, zz, zz};

  STAGE(0, 0);
  int buf = 0;
  for (int s = 0; s < 16; ++s) {
    __syncthreads();                       // drains this buf's DMA (vmcnt 0)
    if (s + 1 < 16) STAGE(s + 1, buf ^ 1); // overlaps with compute below
    short8 aF[2];
#pragma unroll
    for (int h = 0; h < 2; ++h) {
      const int ai = (wr * 4 + 2 * h + (quad >> 1)) * 256 + (ln * 4 + (quad & 1) * 2) * 4;
      const float4v lo = *(const float4v*)&As[buf][ai];
      const float4v hi = *(const float4v*)&As[buf][ai + 4];
      aF[h] = cvt8(lo, hi);
    }
#pragma unroll
    for (int f = 0; f < 6; ++f) {
      const int cf = wc * 6 + f;
      const short8 b0 = *(const short8*)&Bs[buf][(cf * 16 + ln) * 32 + quad * 8];
      const short8 b1 = *(const short8*)&Bs[buf][6144 + (cf * 16 + ln) * 32 + quad * 8];
      if (wc == 0 || f < 2) {
        acc[f] = MFMA16(aF[0], b0, acc[f]);
        acc[f] = MFMA16(aF[1], b1, acc[f]);
      } else {  // V frags: operand swap -> transposed output
        acc[f] = MFMA16(b0, aF[0], acc[f]);
        acc[f] = MFMA16(b1, aF[1], acc[f]);
      }
    }
    buf ^= 1;
  }
#undef STAGE

  const int b  = m0 >> 12;
  const int sb = m0 & (S_LEN - 1);
  if (wc == 0) {
#pragma unroll
    for (int f = 0; f < 6; ++f)
#pragma unroll
      for (int r = 0; r < 4; ++r) {
        const int row = m0 + wr * 16 + quad * 4 + r;
        if (f < 4) Qb[(size_t)row * DD + f * 16 + ln] = f2bf(acc[f][r]);
        else       Kb[(size_t)row * DD + (f - 4) * 16 + ln] = f2bf(acc[f][r]);
      }
  } else {
#pragma unroll
    for (int f = 0; f < 2; ++f)
#pragma unroll
      for (int r = 0; r < 4; ++r) {
        const int row = m0 + wr * 16 + quad * 4 + r;
        Kb[(size_t)row * DD + 32 + f * 16 + ln] = f2bf(acc[f][r]);
      }
#pragma unroll
    for (int f = 2; f < 6; ++f)
#pragma unroll
      for (int r = 0; r < 4; ++r) {
        const int d = (f - 2) * 16 + quad * 4 + r;
        Vt[((size_t)b * DD + d) * S_LEN + sb + wr * 16 + ln] = f2bf(acc[f][r]);
      }
  }
}

// ======================= Kernel 2: causal flash attention =======================
// 256 blocks x 512 thr. Band-paired (j, 127-j) phases -> uniform work.
// Round 7: raw v_exp_f32 via __builtin_amdgcn_exp2f (was libm exp2f -- the
// 45-us version spent ~60% of its VALU cycles in libm exp), diagonal-mask
// hoisted to a wave-uniform branch, rcp epilogue.
#define PSTRW 76

__global__ __launch_bounds__(512, 2) void attn_kernel(
    const short* __restrict__ Qb, const short* __restrict__ Kb,
    const short* __restrict__ Vt, float* __restrict__ out) {
  __shared__ float sbuf[8][32 * PSTRW];
  __shared__ float llds[8][32];

  const int tid  = threadIdx.x;
  const int w    = tid >> 6;
  const int lane = tid & 63;
  const int ln   = lane & 15;
  const int quad = lane >> 4;
  const int g    = blockIdx.x;
  const int b    = g & 3;
  const int j    = g >> 2;
  const short* Kbase = Kb + (size_t)b * S_LEN * DD;
  const short* Vbase = Vt + (size_t)b * DD * S_LEN;
  float* pw = &sbuf[w][0];
  const float4v zz = {0.f, 0.f, 0.f, 0.f};

  for (int ph = 0; ph < 2; ++ph) {
    const int band = ph ? (127 - j) : j;
    const int qb   = band * 32;
    const int qg0  = b * S_LEN + qb;

    short8 aQ[2][2];
#pragma unroll
    for (int rfi = 0; rfi < 2; ++rfi)
#pragma unroll
      for (int h = 0; h < 2; ++h)
        aQ[rfi][h] = *(const short8*)(Qb + (size_t)(qg0 + rfi * 16 + ln) * DD + h * 32 + quad * 8);

    float4v o[2][4];
    float lp[2][4];
#pragma unroll
    for (int rfi = 0; rfi < 2; ++rfi)
#pragma unroll
      for (int d = 0; d < 4; ++d) { o[rfi][d] = zz; lp[rfi][d] = 0.f; }

    const int T = (qb + 95) >> 6;

    short8 Kc[4][2], Kn[4][2];
#pragma unroll
    for (int c = 0; c < 4; ++c)
#pragma unroll
      for (int h = 0; h < 2; ++h)
        Kc[c][h] = *(const short8*)(Kbase + (size_t)(w * 64 + c * 16 + ln) * DD + h * 32 + quad * 8);

    for (int it = w; it < T; it += 8) {
      const int kv0 = it * 64;
      short8 Vc[4][2];
#pragma unroll
      for (int d = 0; d < 4; ++d)
#pragma unroll
        for (int h = 0; h < 2; ++h)
          Vc[d][h] = *(const short8*)(Vbase + (size_t)(d * 16 + ln) * S_LEN + kv0 + h * 32 + quad * 8);

      float4v s[2][4];
#pragma unroll
      for (int rfi = 0; rfi < 2; ++rfi)
#pragma unroll
        for (int c = 0; c < 4; ++c) {
          s[rfi][c] = MFMA16(aQ[rfi][0], Kc[c][0], zz);
          s[rfi][c] = MFMA16(aQ[rfi][1], Kc[c][1], s[rfi][c]);
        }

      const int kvn = (it + 8 < T) ? (it + 8) * 64 : 0;
#pragma unroll
      for (int c = 0; c < 4; ++c)
#pragma unroll
        for (int h = 0; h < 2; ++h)
          Kn[c][h] = *(const short8*)(Kbase + (size_t)(kvn + c * 16 + ln) * DD + h * 32 + quad * 8);

      // P = exp2(S) (scores pre-scaled to log2 domain); single v_exp_f32 each.
      // Mask branch is wave-uniform: only the diagonal tile takes it.
      if ((kv0 + 63) > qb) {
#pragma unroll
        for (int rfi = 0; rfi < 2; ++rfi)
#pragma unroll
          for (int c = 0; c < 4; ++c)
#pragma unroll
            for (int r = 0; r < 4; ++r) {
              float e = __builtin_amdgcn_exp2f(fminf(s[rfi][c][r], 60.0f));
              if (kv0 + c * 16 + ln > qb + rfi * 16 + quad * 4 + r) e = 0.f;
              s[rfi][c][r] = e;
            }
      } else {
#pragma unroll
        for (int rfi = 0; rfi < 2; ++rfi)
#pragma unroll
          for (int c = 0; c < 4; ++c)
#pragma unroll
            for (int r = 0; r < 4; ++r)
              s[rfi][c][r] = __builtin_amdgcn_exp2f(fminf(s[rfi][c][r], 60.0f));
      }

#pragma unroll
      for (int rfi = 0; rfi < 2; ++rfi) {
#pragma unroll
        for (int r = 0; r < 4; ++r)
          lp[rfi][r] += s[rfi][0][r] + s[rfi][1][r] + s[rfi][2][r] + s[rfi][3][r];
#pragma unroll
        for (int c = 0; c < 4; ++c)
#pragma unroll
          for (int r = 0; r < 4; ++r)
            pw[(rfi * 16 + quad * 4 + r) * PSTRW + c * 16 + ln] = s[rfi][c][r];
      }
      asm volatile("s_waitcnt lgkmcnt(0)" ::: "memory");
      short8 aP[2][2];
#pragma unroll
      for (int rfi = 0; rfi < 2; ++rfi)
#pragma unroll
        for (int h = 0; h < 2; ++h) {
          const float4v lo = *(const float4v*)&pw[(rfi * 16 + ln) * PSTRW + h * 32 + quad * 8];
          const float4v hi = *(const float4v*)&pw[(rfi * 16 + ln) * PSTRW + h * 32 + quad * 8 + 4];
          aP[rfi][h] = cvt8(lo, hi);
        }
#pragma unroll
      for (int rfi = 0; rfi < 2; ++rfi)
#pragma unroll
        for (int d = 0; d < 4; ++d) {
          o[rfi][d] = MFMA16(aP[rfi][0], Vc[d][0], o[rfi][d]);
          o[rfi][d] = MFMA16(aP[rfi][1], Vc[d][1], o[rfi][d]);
        }
#pragma unroll
      for (int c = 0; c < 4; ++c)
#pragma unroll
        for (int h = 0; h < 2; ++h)
          Kc[c][h] = Kn[c][h];
    }

#pragma unroll
    for (int rfi = 0; rfi < 2; ++rfi)
#pragma unroll
      for (int r = 0; r < 4; ++r) {
        float lr = lp[rfi][r];
        lr += __shfl_xor(lr, 1);
        lr += __shfl_xor(lr, 2);
        lr += __shfl_xor(lr, 4);
        lr += __shfl_xor(lr, 8);
        if (ln == 0) llds[w][rfi * 16 + quad * 4 + r] = lr;
#pragma unroll
        for (int d = 0; d < 4; ++d)
          pw[(rfi * 16 + quad * 4 + r) * 64 + d * 16 + ln] = o[rfi][d][r];
      }
    __syncthreads();

#pragma unroll
    for (int jj = 0; jj < 4; ++jj) {
      const int idx = tid + jj * 512;
      const int row = idx >> 6, col = idx & 63;
      float sum = 0.f, lt = 0.f;
#pragma unroll
      for (int wi = 0; wi < 8; ++wi) {
        sum += sbuf[wi][row * 64 + col];
        lt  += llds[wi][row];
      }
      out[(size_t)(qg0 + row) * DD + col] = sum * __builtin_amdgcn_rcpf(lt);
    }
    __syncthreads();
  }
}

extern "C" void kernel_launch(void* const* d_in, const int* in_sizes, int n_in,
                              void* d_out, int out_size, void* d_ws, size_t ws_size,
                              hipStream_t stream) {
  const float* x  = (const float*)d_in[0];
  const float* Wq = (const float*)d_in[1];
  const float* Wk = (const float*)d_in[2];
  const float* Wv = (const float*)d_in[3];

  short* Qb  = (short*)d_ws;                       // 2 MB
  short* Kb  = Qb + (size_t)NROWS * DD;            // 2 MB
  short* Vt  = Kb + (size_t)NROWS * DD;            // 2 MB  [b][d][s]
  short* Wb2 = Vt + (size_t)NROWS * DD;            // 384 KB panels

  wcvt_kernel<<<dim3(96), dim3(256), 0, stream>>>(Wq, Wk, Wv, Wb2);
  qkv_kernel<<<dim3(NROWS / 32), dim3(256), 0, stream>>>(x, Wb2, Qb, Kb, Vt);
  attn_kernel<<<dim3(NBATCH * 64), dim3(512), 0, stream>>>(Qb, Kb, Vt, (float*)d_out);
}